// Round 8
// baseline (318.252 us; speedup 1.0000x reference)
//
#include <hip/hip_runtime.h>
#include <math.h>

// MoBA attention, round 7: attention single-barrier-per-chunk —
// V direct global->register (prefetched, L2-local), vbuf/clist removed,
// s_uni aliased into kbuf => LDS exactly 40960 B -> 4 wgs/CU, arithmetic
// chunk advance (wg-uniform), qtile scatter for tail balance.
// GEMMs/selection unchanged from round 6 (passing).

#define HID   768
#define NH    12
#define DH    64
#define SEQN  2048
#define BATCH 2
#define NTOK  (BATCH*SEQN)   // 4096
#define NB    8
#define BLKSZ 256
#define NEG_INF (-__builtin_huge_valf())
#define POS_INF (__builtin_huge_valf())
#define LO_SCALE 2048.0f
#define LO_INV   (1.0f/2048.0f)
#define EXP2C    0.18033688f   // 0.125 * log2(e)

typedef unsigned short u16;
typedef _Float16 v8hf __attribute__((ext_vector_type(8)));
typedef float    v4f  __attribute__((ext_vector_type(4)));

__device__ __forceinline__ u16 f2h(float x) {
    _Float16 h = (_Float16)x;
    return __builtin_bit_cast(u16, h);
}
__device__ __forceinline__ float h2f(u16 u) {
    return (float)__builtin_bit_cast(_Float16, u);
}
__device__ __forceinline__ v8hf ldhf8(const u16* p) {
    return *reinterpret_cast<const v8hf*>(p);
}
__device__ __forceinline__ void g2lds16(const u16* g, u16* l) {
    __builtin_amdgcn_global_load_lds(
        (const __attribute__((address_space(1))) void*)g,
        (__attribute__((address_space(3))) void*)l, 16, 0, 0);
}
#define MFMA16(a, b, c) __builtin_amdgcn_mfma_f32_16x16x32_f16(a, b, c, 0, 0, 0)

// ---------------------------------------------------------------------------
__global__ __launch_bounds__(256)
void rope_tab_k(float2* __restrict__ tab)
{
    int i = blockIdx.x * 256 + threadIdx.x;
    if (i >= SEQN * 32) return;
    int s = i >> 5, f = i & 31;
    double y  = exp((double)f * (log(10000.0) / 32.0));
    float  yf = (float)y;
    float  invf = 1.0f / yf;
    float  ang  = (float)s * invf;
    tab[i] = make_float2((float)sin((double)ang), (float)cos((double)ang));
}

// ---------------------------------------------------------------------------
__global__ __launch_bounds__(256)
void xsplit_k(const float* __restrict__ src, int n,
              u16* __restrict__ oh, u16* __restrict__ ol)
{
    int i = blockIdx.x * 256 + threadIdx.x;
    if (i >= n) return;
    float x = src[i];
    u16 h = f2h(x);
    oh[i] = h;
    ol[i] = f2h((x - h2f(h)) * LO_SCALE);
}

__global__ __launch_bounds__(256)
void wsplit_k(const float* __restrict__ Wq, const float* __restrict__ Wk,
              const float* __restrict__ Wv, const float* __restrict__ Wo,
              u16* __restrict__ Wq2, u16* __restrict__ Wk2,
              u16* __restrict__ Wv2, u16* __restrict__ Wo2)
{
    const int NW = HID * HID;
    const int z = blockIdx.y;
    const int i = blockIdx.x * 256 + threadIdx.x;
    const float* src = (z == 0) ? Wq : (z == 1) ? Wk : (z == 2) ? Wv : Wo;
    u16* dst = (z == 0) ? Wq2 : (z == 1) ? Wk2 : (z == 2) ? Wv2 : Wo2;
    float x = src[i];
    u16 h = f2h(x);
    dst[i] = h;
    dst[i + NW] = f2h((x - h2f(h)) * LO_SCALE);
}

// ---------------------------------------------------------------------------
// 128x128 LDS-staged mainloop, f16 3-product: acc = (Al*Bh + Ah*Bl)/2048 + Ah*Bh.
__device__ __forceinline__
void gemm_mainloop(const u16* __restrict__ Ah, const u16* __restrict__ Al,
                   const u16* __restrict__ Bh, const u16* __restrict__ Bl,
                   int m0, int nb0, u16* As, u16* Bs, v4f acc[4][4])
{
    const int tid  = threadIdx.x;
    const int wave = tid >> 6, lane = tid & 63;
    const int col  = lane & 15, quad = lane >> 4;
    const int wr   = wave >> 1, wc = wave & 1;

    int ld_row[4], ld_gl[4];
    #pragma unroll
    for (int r = 0; r < 4; r++) {
        int g = r * 256 + tid;
        ld_row[r] = g >> 3;
        ld_gl[r]  = (g & 7) ^ (ld_row[r] & 7);
    }

    #pragma unroll
    for (int c = 0; c < 3; c++) {
        const u16* Ap = (c == 0) ? Al : Ah;
        const u16* Bp = (c == 1) ? Bl : Bh;
        for (int itc = 0; itc < HID / 64; itc++) {
            const int k0 = itc * 64;
            __syncthreads();
            #pragma unroll
            for (int r = 0; r < 4; r++) {
                g2lds16(Ap + (size_t)(m0 + ld_row[r]) * HID + k0 + ld_gl[r] * 8,
                        &As[(r * 256 + wave * 64) * 8]);
                g2lds16(Bp + (size_t)(nb0 + ld_row[r]) * HID + k0 + ld_gl[r] * 8,
                        &Bs[(r * 256 + wave * 64) * 8]);
            }
            __syncthreads();
            #pragma unroll
            for (int ks = 0; ks < 2; ks++) {
                v8hf af[4], bf_[4];
                #pragma unroll
                for (int mt = 0; mt < 4; mt++) {
                    const int row = wr * 64 + mt * 16 + col;
                    const int gph = (ks * 4 + quad) ^ (row & 7);
                    af[mt] = ldhf8(&As[row * 64 + gph * 8]);
                }
                #pragma unroll
                for (int nt = 0; nt < 4; nt++) {
                    const int row = wc * 64 + nt * 16 + col;
                    const int gph = (ks * 4 + quad) ^ (row & 7);
                    bf_[nt] = ldhf8(&Bs[row * 64 + gph * 8]);
                }
                #pragma unroll
                for (int mt = 0; mt < 4; mt++)
                    #pragma unroll
                    for (int nt = 0; nt < 4; nt++)
                        acc[mt][nt] = MFMA16(af[mt], bf_[nt], acc[mt][nt]);
            }
        }
        if (c == 1) {
            #pragma unroll
            for (int mt = 0; mt < 4; mt++)
                #pragma unroll
                for (int nt = 0; nt < 4; nt++)
                    #pragma unroll
                    for (int r = 0; r < 4; r++)
                        acc[mt][nt][r] *= LO_INV;
        }
    }
    __syncthreads();
}

// ---------------------------------------------------------------------------
__global__ __launch_bounds__(256)
void qkv_fused_gemm_k(const u16* __restrict__ Xh, const u16* __restrict__ Xl,
                      const u16* __restrict__ Wq2, const u16* __restrict__ Wk2,
                      const u16* __restrict__ Wv2, const float2* __restrict__ tab,
                      float* __restrict__ q32,
                      u16* __restrict__ kh16, u16* __restrict__ kl16,
                      u16* __restrict__ vth, float* __restrict__ partial)
{
    __shared__ u16 As[128 * 64];
    __shared__ u16 Bs[128 * 64];
    __shared__ float psum[2][2][64];

    const int NW = HID * HID;
    const int id    = blockIdx.x;
    const int xcd   = id & 7, loc = id >> 3;
    const int mtile = xcd * 4 + (loc & 3);
    const int ntile = loc >> 2;
    const int m0 = mtile * 128;
    const int n0 = ntile * 128;
    const int mat = n0 / HID;
    const int nb0 = n0 - mat * HID;
    const u16* Bh = (mat == 0) ? Wq2 : (mat == 1) ? Wk2 : Wv2;

    v4f acc[4][4] = {};
    gemm_mainloop(Xh, Xl, Bh, Bh + NW, m0, nb0, As, Bs, acc);

    const int tid  = threadIdx.x;
    const int wave = tid >> 6, lane = tid & 63;
    const int col  = lane & 15, quad = lane >> 4;
    const int wr   = wave >> 1, wc = wave & 1;
    const int b    = m0 >> 11;
    const int h    = (nb0 + wc * 64) >> 6;
    const size_t bh = (size_t)b * NH + h;

    if (mat == 2) {
        #pragma unroll
        for (int nt = 0; nt < 4; nt++) {
            const int d = nt * 16 + col;
            #pragma unroll
            for (int mt = 0; mt < 4; mt++) {
                const int m = m0 + wr * 64 + mt * 16 + quad * 4;
                const int s = m & (SEQN - 1);
                ushort4 pk = make_ushort4(f2h(acc[mt][nt][0]), f2h(acc[mt][nt][1]),
                                          f2h(acc[mt][nt][2]), f2h(acc[mt][nt][3]));
                *(ushort4*)&vth[(bh * DH + d) * SEQN + s] = pk;
            }
        }
        return;
    }

    float vsum[4] = {0.f, 0.f, 0.f, 0.f};
    #pragma unroll
    for (int mt = 0; mt < 4; mt++) {
        #pragma unroll
        for (int nt = 0; nt < 4; nt++) {
            const int d = nt * 16 + col;
            #pragma unroll
            for (int r = 0; r < 4; r++) {
                const int m = m0 + wr * 64 + mt * 16 + quad * 4 + r;
                const int s = m & (SEQN - 1);
                const float part = acc[mt][nt ^ 2][r];
                const float2 sc = tab[(s << 5) + (d & 31)];
                const float val = (d < 32) ? acc[mt][nt][r] * sc.y - part * sc.x
                                           : acc[mt][nt][r] * sc.y + part * sc.x;
                const size_t idx = (bh * SEQN + s) * DH + d;
                if (mat == 0) {
                    q32[idx] = val;
                } else {
                    u16 hb = f2h(val);
                    kh16[idx] = hb;
                    kl16[idx] = f2h((val - h2f(hb)) * LO_SCALE);
                    vsum[nt] += val;
                }
            }
        }
    }
    if (mat == 1) {
        #pragma unroll
        for (int nt = 0; nt < 4; nt++) {
            float v = vsum[nt];
            v += __shfl_xor(v, 16);
            v += __shfl_xor(v, 32);
            if (quad == 0) psum[wr][wc][nt * 16 + col] = v;
        }
        __syncthreads();
        if (tid < 128) {
            const int wc2 = tid >> 6, d = tid & 63;
            const float s2 = psum[0][wc2][d] + psum[1][wc2][d];
            const int h2 = (nb0 + wc2 * 64) >> 6;
            const int nblk = (m0 & (SEQN - 1)) >> 8;
            const int half = (m0 >> 7) & 1;
            partial[((((size_t)b * NH + h2) * NB + nblk) * 2 + half) * 64 + d] = s2;
        }
    }
}

// ---------------------------------------------------------------------------
__global__ __launch_bounds__(256)
void out_gemm_mfma_k(const u16* __restrict__ Ah, const u16* __restrict__ Al,
                     const u16* __restrict__ Wo2, float* __restrict__ C)
{
    __shared__ u16 As[128 * 64];
    __shared__ u16 Bs[128 * 64];

    const int NW = HID * HID;
    const int id    = blockIdx.x;
    const int xcd   = id & 7, loc = id >> 3;
    const int mtile = xcd * 4 + (loc & 3);
    const int ntile = loc >> 2;
    const int m0 = mtile * 128;
    const int n0 = ntile * 128;

    v4f acc[4][4] = {};
    gemm_mainloop(Ah, Al, Wo2, Wo2 + NW, m0, n0, As, Bs, acc);

    const int tid  = threadIdx.x;
    const int wave = tid >> 6, lane = tid & 63;
    const int col  = lane & 15, quad = lane >> 4;
    const int wr   = wave >> 1, wc = wave & 1;

    #pragma unroll
    for (int mt = 0; mt < 4; mt++)
        #pragma unroll
        for (int nt = 0; nt < 4; nt++)
            #pragma unroll
            for (int r = 0; r < 4; r++) {
                const int m = m0 + wr * 64 + mt * 16 + quad * 4 + r;
                C[(size_t)m * HID + n0 + wc * 64 + nt * 16 + col] = acc[mt][nt][r];
            }
}

// ---------------------------------------------------------------------------
__global__ __launch_bounds__(64)
void reps_reduce_k(const float* __restrict__ partial, float* __restrict__ reps)
{
    const int bhn = blockIdx.x;
    const int d = threadIdx.x;
    const float* p = &partial[(size_t)bhn * 128 + d];
    double s = (double)p[0] + (double)p[64];
    reps[(size_t)bhn * 64 + d] = (float)(s * (1.0 / 256.0));
}

// ---------------------------------------------------------------------------
__global__ __launch_bounds__(128)
void select_topk_k(const float* __restrict__ qg, const float* __restrict__ reps,
                   unsigned* __restrict__ selm)
{
    __shared__ float rs[NB][DH];
    const int bh = blockIdx.y;
    const int tid = threadIdx.x;
    for (int idx = tid; idx < NB * DH; idx += 128)
        rs[idx >> 6][idx & 63] = reps[(size_t)bh * NB * DH + idx];
    __syncthreads();

    const int qq = blockIdx.x * 128 + tid;
    const float* qv = &qg[((size_t)bh * SEQN + qq) * DH];
    float qr[DH];
    #pragma unroll
    for (int c = 0; c < 16; c++) {
        float4 t = *(const float4*)&qv[c * 4];
        qr[c*4+0]=t.x; qr[c*4+1]=t.y; qr[c*4+2]=t.z; qr[c*4+3]=t.w;
    }
    const int cur = qq >> 8;
    double sc[NB];
    #pragma unroll
    for (int n = 0; n < NB; n++) {
        double ssum = 0.0;
        for (int d = 0; d < DH; d++) ssum += (double)qr[d] * (double)rs[n][d];
        sc[n] = ssum * 0.125;
    }
    for (int n = cur + 1; n < NB; n++) sc[n] = -1e300;
    sc[cur] = 1e300;
    unsigned mask = 0;
    for (int p = 0; p < 3; p++) {
        int bi = -1; double bv = 0.0;
        for (int n = 0; n < NB; n++) {
            if ((mask >> n) & 1) continue;
            if (bi < 0 || sc[n] > bv) { bi = n; bv = sc[n]; }
        }
        mask |= 1u << bi;
    }
    selm[(size_t)bh * SEQN + qq] = mask;
}

// ---------------------------------------------------------------------------
// f16 MFMA flash attention, single barrier per chunk.
// K hi/lo double-buffered via global_load_lds (32 KB); V direct global->reg
// (prefetched after barrier, L2-local); P wave-private LDS (fence only);
// wg-uniform arithmetic chunk advance; qtile scattered for tail balance.
__global__ __launch_bounds__(256, 4)
void moba_attn_k(const float* __restrict__ q32,
                 const u16* __restrict__ kh16, const u16* __restrict__ kl16,
                 const u16* __restrict__ vth, const unsigned* __restrict__ selm,
                 u16* __restrict__ aoh, u16* __restrict__ aol)
{
    __shared__ u16 kbuf[2][2][64 * 64];   // 32 KB, dbuf
    __shared__ u16 plds[4][16][64];       // 8 KB, per-wave P
    unsigned* s_uni = (unsigned*)&kbuf[1][0][0];  // alias: dead until stage(1)

    const int id  = blockIdx.x;                 // 768
    const int xcd = id & 7, loc = id >> 3;      // 96 per XCD
    const int bhl = loc >> 5;
    const int bh  = xcd * 3 + bhl;              // 3 bh per XCD (L2-local K/V)
    const int qt  = ((loc & 31) * 5 + bhl * 11) & 31;   // scatter for balance
    const int q0  = qt * 64;
    const int cur = q0 >> 8;
    const int tid = threadIdx.x;
    const int wave = tid >> 6, lane = tid & 63;
    const int col = lane & 15, quad = lane >> 4;
    const int qw0 = q0 + wave * 16;
    const int qpos = qw0 + col;
    const size_t bhS = (size_t)bh * SEQN;
    const size_t bhV = (size_t)bh * DH;

    if (tid == 0) *s_uni = 0;
    __syncthreads();
    const unsigned mymask = selm[bhS + qw0 + col];
    unsigned uw = mymask;
    #pragma unroll
    for (int off = 1; off < 16; off <<= 1) uw |= __shfl_xor(uw, off);
    if (lane == 0) atomicOr(s_uni, uw);

    // Q fragments: f16 2-split, lo prescaled x2048
    v8hf qh[2], ql[2];
    #pragma unroll
    for (int ks = 0; ks < 2; ks++) {
        const float* qp = &q32[(bhS + qw0 + col) * DH + ks * 32 + quad * 8];
        float4 f0 = *(const float4*)qp;
        float4 f1 = *(const float4*)(qp + 4);
        float qf[8] = {f0.x, f0.y, f0.z, f0.w, f1.x, f1.y, f1.z, f1.w};
        union { u16 u[8]; v8hf h; } uh, ul;
        #pragma unroll
        for (int j = 0; j < 8; j++) {
            u16 hb = f2h(qf[j]);
            uh.u[j] = hb;
            ul.u[j] = f2h((qf[j] - h2f(hb)) * LO_SCALE);
        }
        qh[ks] = uh.h; ql[ks] = ul.h;
    }
    __syncthreads();
    const unsigned uni = *s_uni;     // consumed before stage(1) overwrites alias
    __syncthreads();

    // wg-uniform chunk enumeration state
    int n_cur = __builtin_ctz(uni), c_cur = 0;
    int n_nxt = n_cur, c_nxt = 0;
    bool has_nxt = true;
    auto c2max = [&](int n) { return (n == cur) ? ((q0 + 63 - n * BLKSZ) >> 6) : 3; };
    auto advance = [&]() {
        if (c_nxt < c2max(n_nxt)) { c_nxt++; return; }
        has_nxt = false;
        for (int nn = n_nxt + 1; nn < NB; nn++)
            if ((uni >> nn) & 1) { n_nxt = nn; c_nxt = 0; has_nxt = true; return; }
    };
    advance();

    // K staging (granule g = tid covers rows 0-31; +256 rows 32-63)
    const int sg_row0 = tid >> 3;
    const int sg_gl0  = (tid & 7) ^ (sg_row0 & 7);
    const int sg_row1 = (256 + tid) >> 3;
    const int sg_gl1  = ((256 + tid) & 7) ^ (sg_row1 & 7);
    auto stageK = [&](int n, int c2, int buf) {
        const int kb = n * BLKSZ + c2 * 64;
        u16* k0 = (u16*)kbuf[buf][0];
        u16* k1 = (u16*)kbuf[buf][1];
        const size_t ks0 = (bhS + kb + sg_row0) * DH + sg_gl0 * 8;
        const size_t ks1 = (bhS + kb + sg_row1) * DH + sg_gl1 * 8;
        g2lds16(kh16 + ks0, k0 + (wave * 64) * 8);
        g2lds16(kh16 + ks1, k0 + (256 + wave * 64) * 8);
        g2lds16(kl16 + ks0, k1 + (wave * 64) * 8);
        g2lds16(kl16 + ks1, k1 + (256 + wave * 64) * 8);
    };

    const v4f zero4 = {0.f, 0.f, 0.f, 0.f};
    v4f oacc[4] = {zero4, zero4, zero4, zero4};
    float m_i = NEG_INF, l_i = 0.f;
    const int psw = (col & 7) << 1;

    stageK(n_cur, c_cur, 0);
    int t = 0;
    while (true) {
        __syncthreads();                       // K(t) staged; buf (t+1)&1 free
        if (has_nxt) stageK(n_nxt, c_nxt, (t + 1) & 1);

        const int n  = n_cur;
        const int kb = n * BLKSZ + c_cur * 64;

        // ---- V prefetch: direct global (L2-local), consumed at PV
        v8hf vr[2][4];
        #pragma unroll
        for (int ks2 = 0; ks2 < 2; ks2++)
            #pragma unroll
            for (int nt = 0; nt < 4; nt++)
                vr[ks2][nt] = ldhf8(&vth[(bhV + nt * 16 + col) * SEQN
                                         + kb + ks2 * 32 + quad * 8]);

        const bool iscur = (n == cur);
        const float selinf = ((mymask >> n) & 1) ? 0.f : POS_INF;
        const bool need_mask = iscur && (kb + 63 > qw0);
        const u16* k0 = (const u16*)kbuf[t & 1][0];
        const u16* k1 = (const u16*)kbuf[t & 1][1];

        // ---- S^T[64k x 16q]: (Kl*Qh + Kh*Ql)/2048 + Kh*Qh
        v4f sf[4];
        #pragma unroll
        for (int mt = 0; mt < 4; mt++) {
            const int row = mt * 16 + col;
            const int r7 = row & 7;
            v8hf kh0 = ldhf8(&k0[(row * 8 + (quad ^ r7)) * 8]);
            v8hf kh1 = ldhf8(&k0[(row * 8 + ((4 + quad) ^ r7)) * 8]);
            v8hf kl0 = ldhf8(&k1[(row * 8 + (quad ^ r7)) * 8]);
            v8hf kl1 = ldhf8(&k1[(row * 8 + ((4 + quad) ^ r7)) * 8]);
            v4f c = zero4;
            c = MFMA16(kl0, qh[0], c);
            c = MFMA16(kl1, qh[1], c);
            c = MFMA16(kh0, ql[0], c);
            c = MFMA16(kh1, ql[1], c);
            #pragma unroll
            for (int r = 0; r < 4; r++) c[r] *= LO_INV;
            c = MFMA16(kh0, qh[0], c);
            c = MFMA16(kh1, qh[1], c);
            sf[mt] = c;
        }

        if (need_mask) {
            #pragma unroll
            for (int mt = 0; mt < 4; mt++)
                #pragma unroll
                for (int r = 0; r < 4; r++) {
                    const int kidx = kb + mt * 16 + quad * 4 + r;
                    sf[mt][r] = (kidx <= qpos) ? sf[mt][r] : NEG_INF;
                }
        }

        // ---- softmax (exp2, folded 0.125 scale)
        float rm = NEG_INF;
        #pragma unroll
        for (int mt = 0; mt < 4; mt++)
            #pragma unroll
            for (int r = 0; r < 4; r++) rm = fmaxf(rm, sf[mt][r]);
        rm = fmaxf(rm, __shfl_xor(rm, 16));
        rm = fmaxf(rm, __shfl_xor(rm, 32));
        rm = rm - selinf;
        const float mnew  = fmaxf(m_i, rm);
        const float alpha = (m_i == NEG_INF) ? 0.f : exp2f((m_i - mnew) * EXP2C);
        const float biasC = ((mnew == NEG_INF) ? 0.f : mnew * EXP2C) + selinf;

        float lsum = 0.f;
        #pragma unroll
        for (int mt = 0; mt < 4; mt++) {
            ushort4 hv;
            #pragma unroll
            for (int r = 0; r < 4; r++) {
                float p = exp2f(fmaf(sf[mt][r], EXP2C, -biasC));
                lsum += p;
                u16 hu = f2h(p);
                if (r == 0) hv.x = hu;
                else if (r == 1) hv.y = hu;
                else if (r == 2) hv.z = hu;
                else hv.w = hu;
            }
            *(ushort4*)&plds[wave][col][((mt * 4 + quad) ^ psw) * 4] = hv;
        }
        lsum += __shfl_xor(lsum, 16);
        lsum += __shfl_xor(lsum, 32);
        l_i = l_i * alpha + lsum;
        m_i = mnew;

        float ar[4];
        #pragma unroll
        for (int r = 0; r < 4; r++) ar[r] = __shfl(alpha, quad * 4 + r, 16);
        #pragma unroll
        for (int nt = 0; nt < 4; nt++)
            #pragma unroll
            for (int r = 0; r < 4; r++) oacc[nt][r] *= ar[r];

        __threadfence_block();   // wave-private P: write->read ordering

        // ---- O += P * V  (P from wave-private LDS; V from registers)
        #pragma unroll
        for (int ks2 = 0; ks2 < 2; ks2++) {
            v8hf ph = ldhf8(&plds[wave][col][((ks2 * 8 + quad * 2) ^ psw) * 4]);
            #pragma unroll
            for (int nt = 0; nt < 4; nt++)
                oacc[nt] = MFMA16(ph, vr[ks2][nt], oacc[nt]);
        }

        if (!has_nxt) break;
        n_cur = n_nxt; c_cur = c_nxt;
        advance();
        t++;
    }

    // ---- epilogue: normalize, f16 2-split store
    const int b = bh / NH, h = bh % NH;
    const float invl = 1.f / l_i;
    float ir[4];
    #pragma unroll
    for (int r = 0; r < 4; r++) ir[r] = __shfl(invl, quad * 4 + r, 16);
    #pragma unroll
    for (int nt = 0; nt < 4; nt++)
        #pragma unroll
        for (int r = 0; r < 4; r++) {
            const int qi = qw0 + quad * 4 + r;
            const size_t idx = ((size_t)b * SEQN + qi) * HID + h * DH + nt * 16 + col;
            float val = oacc[nt][r] * ir[r];
            u16 hb = f2h(val);
            aoh[idx] = hb;
            aol[idx] = f2h((val - h2f(hb)) * LO_SCALE);
        }
}

// ---------------------------------------------------------------------------
extern "C" void kernel_launch(void* const* d_in, const int* in_sizes, int n_in,
                              void* d_out, int out_size, void* d_ws, size_t ws_size,
                              hipStream_t stream)
{
    const float* X  = (const float*)d_in[0];
    const float* Wq = (const float*)d_in[1];
    const float* Wk = (const float*)d_in[2];
    const float* Wv = (const float*)d_in[3];
    const float* Wo = (const float*)d_in[4];
    float* out = (float*)d_out;

    char* p = (char*)d_ws;
    float* q32 = (float*)p;                p += (size_t)NTOK*HID*4;
    u16* kh16 = (u16*)p;                   p += (size_t)NTOK*HID*2;
    u16* kl16 = (u16*)p;                   p += (size_t)NTOK*HID*2;
    u16* vth  = (u16*)p;                   p += (size_t)NTOK*HID*2;
    u16* Xh   = (u16*)p;                   p += (size_t)NTOK*HID*2;   // aoh alias
    u16* Xl   = (u16*)p;                   p += (size_t)NTOK*HID*2;   // aol alias
    u16* Wq2  = (u16*)p;                   p += (size_t)HID*HID*2*2;
    u16* Wk2  = (u16*)p;                   p += (size_t)HID*HID*2*2;
    u16* Wv2  = (u16*)p;                   p += (size_t)HID*HID*2*2;
    u16* Wo2  = (u16*)p;                   p += (size_t)HID*HID*2*2;
    float* partial = (float*)p;            p += (size_t)BATCH*NH*NB*2*64*4;
    float* reps    = (float*)p;            p += (size_t)BATCH*NH*NB*DH*4;
    unsigned* selm = (unsigned*)p;         p += (size_t)BATCH*NH*SEQN*4;
    float2* tab    = (float2*)p;           p += (size_t)SEQN*32*8;
    u16* aoh = Xh;
    u16* aol = Xl;

    const int NX = NTOK*HID;
    const int NW = HID*HID;

    rope_tab_k<<<dim3((SEQN*32+255)/256), 256, 0, stream>>>(tab);
    xsplit_k<<<dim3((NX+255)/256), 256, 0, stream>>>(X, NX, Xh, Xl);
    wsplit_k<<<dim3(NW/256, 4), 256, 0, stream>>>(Wq, Wk, Wv, Wo,
                                                  Wq2, Wk2, Wv2, Wo2);

    qkv_fused_gemm_k<<<dim3(576), 256, 0, stream>>>(
        Xh, Xl, Wq2, Wk2, Wv2, tab, q32, kh16, kl16, vth, partial);

    reps_reduce_k<<<dim3(BATCH*NH*NB), 64, 0, stream>>>(partial, reps);
    select_topk_k<<<dim3(SEQN/128, BATCH*NH), 128, 0, stream>>>(q32, reps, selm);

    moba_attn_k<<<dim3(BATCH*NH*(SEQN/64)), 256, 0, stream>>>(
        q32, kh16, kl16, vth, selm, aoh, aol);

    out_gemm_mfma_k<<<dim3(192), 256, 0, stream>>>(aoh, Xl, Wo2, out);
}

// Round 9
// 269.517 us; speedup vs baseline: 1.1808x; 1.1808x over previous
//
#include <hip/hip_runtime.h>
#include <math.h>

// MoBA attention, round 8: attention K-hi-only scores (error-budget trade),
// K+V both double-buffered in LDS (40960 B exactly -> 4 wgs/CU), single
// barrier per chunk, no V register prefetch (r8 regression reverted).
// attn-out f16 single plane -> 2-product out-proj. kl16 plane removed.

#define HID   768
#define NH    12
#define DH    64
#define SEQN  2048
#define BATCH 2
#define NTOK  (BATCH*SEQN)   // 4096
#define NB    8
#define BLKSZ 256
#define NEG_INF (-__builtin_huge_valf())
#define POS_INF (__builtin_huge_valf())
#define LO_SCALE 2048.0f
#define LO_INV   (1.0f/2048.0f)
#define EXP2C    0.18033688f   // 0.125 * log2(e)

typedef unsigned short u16;
typedef _Float16 v8hf __attribute__((ext_vector_type(8)));
typedef float    v4f  __attribute__((ext_vector_type(4)));

__device__ __forceinline__ u16 f2h(float x) {
    _Float16 h = (_Float16)x;
    return __builtin_bit_cast(u16, h);
}
__device__ __forceinline__ float h2f(u16 u) {
    return (float)__builtin_bit_cast(_Float16, u);
}
__device__ __forceinline__ v8hf ldhf8(const u16* p) {
    return *reinterpret_cast<const v8hf*>(p);
}
__device__ __forceinline__ void g2lds16(const u16* g, u16* l) {
    __builtin_amdgcn_global_load_lds(
        (const __attribute__((address_space(1))) void*)g,
        (__attribute__((address_space(3))) void*)l, 16, 0, 0);
}
#define MFMA16(a, b, c) __builtin_amdgcn_mfma_f32_16x16x32_f16(a, b, c, 0, 0, 0)

// ---------------------------------------------------------------------------
__global__ __launch_bounds__(256)
void rope_tab_k(float2* __restrict__ tab)
{
    int i = blockIdx.x * 256 + threadIdx.x;
    if (i >= SEQN * 32) return;
    int s = i >> 5, f = i & 31;
    double y  = exp((double)f * (log(10000.0) / 32.0));
    float  yf = (float)y;
    float  invf = 1.0f / yf;
    float  ang  = (float)s * invf;
    tab[i] = make_float2((float)sin((double)ang), (float)cos((double)ang));
}

// ---------------------------------------------------------------------------
__global__ __launch_bounds__(256)
void xsplit_k(const float* __restrict__ src, int n,
              u16* __restrict__ oh, u16* __restrict__ ol)
{
    int i = blockIdx.x * 256 + threadIdx.x;
    if (i >= n) return;
    float x = src[i];
    u16 h = f2h(x);
    oh[i] = h;
    ol[i] = f2h((x - h2f(h)) * LO_SCALE);
}

__global__ __launch_bounds__(256)
void wsplit_k(const float* __restrict__ Wq, const float* __restrict__ Wk,
              const float* __restrict__ Wv, const float* __restrict__ Wo,
              u16* __restrict__ Wq2, u16* __restrict__ Wk2,
              u16* __restrict__ Wv2, u16* __restrict__ Wo2)
{
    const int NW = HID * HID;
    const int z = blockIdx.y;
    const int i = blockIdx.x * 256 + threadIdx.x;
    const float* src = (z == 0) ? Wq : (z == 1) ? Wk : (z == 2) ? Wv : Wo;
    u16* dst = (z == 0) ? Wq2 : (z == 1) ? Wk2 : (z == 2) ? Wv2 : Wo2;
    float x = src[i];
    u16 h = f2h(x);
    dst[i] = h;
    dst[i + NW] = f2h((x - h2f(h)) * LO_SCALE);
}

// ---------------------------------------------------------------------------
// 128x128 LDS-staged mainloop, 3-product: acc = (Al*Bh + Ah*Bl)/2048 + Ah*Bh.
__device__ __forceinline__
void gemm_mainloop(const u16* __restrict__ Ah, const u16* __restrict__ Al,
                   const u16* __restrict__ Bh, const u16* __restrict__ Bl,
                   int m0, int nb0, u16* As, u16* Bs, v4f acc[4][4])
{
    const int tid  = threadIdx.x;
    const int wave = tid >> 6, lane = tid & 63;
    const int col  = lane & 15, quad = lane >> 4;
    const int wr   = wave >> 1, wc = wave & 1;

    int ld_row[4], ld_gl[4];
    #pragma unroll
    for (int r = 0; r < 4; r++) {
        int g = r * 256 + tid;
        ld_row[r] = g >> 3;
        ld_gl[r]  = (g & 7) ^ (ld_row[r] & 7);
    }

    #pragma unroll
    for (int c = 0; c < 3; c++) {
        const u16* Ap = (c == 0) ? Al : Ah;
        const u16* Bp = (c == 1) ? Bl : Bh;
        for (int itc = 0; itc < HID / 64; itc++) {
            const int k0 = itc * 64;
            __syncthreads();
            #pragma unroll
            for (int r = 0; r < 4; r++) {
                g2lds16(Ap + (size_t)(m0 + ld_row[r]) * HID + k0 + ld_gl[r] * 8,
                        &As[(r * 256 + wave * 64) * 8]);
                g2lds16(Bp + (size_t)(nb0 + ld_row[r]) * HID + k0 + ld_gl[r] * 8,
                        &Bs[(r * 256 + wave * 64) * 8]);
            }
            __syncthreads();
            #pragma unroll
            for (int ks = 0; ks < 2; ks++) {
                v8hf af[4], bf_[4];
                #pragma unroll
                for (int mt = 0; mt < 4; mt++) {
                    const int row = wr * 64 + mt * 16 + col;
                    const int gph = (ks * 4 + quad) ^ (row & 7);
                    af[mt] = ldhf8(&As[row * 64 + gph * 8]);
                }
                #pragma unroll
                for (int nt = 0; nt < 4; nt++) {
                    const int row = wc * 64 + nt * 16 + col;
                    const int gph = (ks * 4 + quad) ^ (row & 7);
                    bf_[nt] = ldhf8(&Bs[row * 64 + gph * 8]);
                }
                #pragma unroll
                for (int mt = 0; mt < 4; mt++)
                    #pragma unroll
                    for (int nt = 0; nt < 4; nt++)
                        acc[mt][nt] = MFMA16(af[mt], bf_[nt], acc[mt][nt]);
            }
        }
        if (c == 1) {
            #pragma unroll
            for (int mt = 0; mt < 4; mt++)
                #pragma unroll
                for (int nt = 0; nt < 4; nt++)
                    #pragma unroll
                    for (int r = 0; r < 4; r++)
                        acc[mt][nt][r] *= LO_INV;
        }
    }
    __syncthreads();
}

// 2-product variant (A single plane): acc = (Ah*Bl)/2048 + Ah*Bh.
__device__ __forceinline__
void gemm_mainloop2(const u16* __restrict__ Ah,
                    const u16* __restrict__ Bh, const u16* __restrict__ Bl,
                    int m0, int nb0, u16* As, u16* Bs, v4f acc[4][4])
{
    const int tid  = threadIdx.x;
    const int wave = tid >> 6, lane = tid & 63;
    const int col  = lane & 15, quad = lane >> 4;
    const int wr   = wave >> 1, wc = wave & 1;

    int ld_row[4], ld_gl[4];
    #pragma unroll
    for (int r = 0; r < 4; r++) {
        int g = r * 256 + tid;
        ld_row[r] = g >> 3;
        ld_gl[r]  = (g & 7) ^ (ld_row[r] & 7);
    }

    #pragma unroll
    for (int c = 0; c < 2; c++) {
        const u16* Bp = (c == 0) ? Bl : Bh;
        for (int itc = 0; itc < HID / 64; itc++) {
            const int k0 = itc * 64;
            __syncthreads();
            #pragma unroll
            for (int r = 0; r < 4; r++) {
                g2lds16(Ah + (size_t)(m0 + ld_row[r]) * HID + k0 + ld_gl[r] * 8,
                        &As[(r * 256 + wave * 64) * 8]);
                g2lds16(Bp + (size_t)(nb0 + ld_row[r]) * HID + k0 + ld_gl[r] * 8,
                        &Bs[(r * 256 + wave * 64) * 8]);
            }
            __syncthreads();
            #pragma unroll
            for (int ks = 0; ks < 2; ks++) {
                v8hf af[4], bf_[4];
                #pragma unroll
                for (int mt = 0; mt < 4; mt++) {
                    const int row = wr * 64 + mt * 16 + col;
                    const int gph = (ks * 4 + quad) ^ (row & 7);
                    af[mt] = ldhf8(&As[row * 64 + gph * 8]);
                }
                #pragma unroll
                for (int nt = 0; nt < 4; nt++) {
                    const int row = wc * 64 + nt * 16 + col;
                    const int gph = (ks * 4 + quad) ^ (row & 7);
                    bf_[nt] = ldhf8(&Bs[row * 64 + gph * 8]);
                }
                #pragma unroll
                for (int mt = 0; mt < 4; mt++)
                    #pragma unroll
                    for (int nt = 0; nt < 4; nt++)
                        acc[mt][nt] = MFMA16(af[mt], bf_[nt], acc[mt][nt]);
            }
        }
        if (c == 0) {
            #pragma unroll
            for (int mt = 0; mt < 4; mt++)
                #pragma unroll
                for (int nt = 0; nt < 4; nt++)
                    #pragma unroll
                    for (int r = 0; r < 4; r++)
                        acc[mt][nt][r] *= LO_INV;
        }
    }
    __syncthreads();
}

// ---------------------------------------------------------------------------
__global__ __launch_bounds__(256)
void qkv_fused_gemm_k(const u16* __restrict__ Xh, const u16* __restrict__ Xl,
                      const u16* __restrict__ Wq2, const u16* __restrict__ Wk2,
                      const u16* __restrict__ Wv2, const float2* __restrict__ tab,
                      float* __restrict__ q32, u16* __restrict__ kh16,
                      u16* __restrict__ vth, float* __restrict__ partial)
{
    __shared__ u16 As[128 * 64];
    __shared__ u16 Bs[128 * 64];
    __shared__ float psum[2][2][64];

    const int NW = HID * HID;
    const int id    = blockIdx.x;
    const int xcd   = id & 7, loc = id >> 3;
    const int mtile = xcd * 4 + (loc & 3);
    const int ntile = loc >> 2;
    const int m0 = mtile * 128;
    const int n0 = ntile * 128;
    const int mat = n0 / HID;
    const int nb0 = n0 - mat * HID;
    const u16* Bh = (mat == 0) ? Wq2 : (mat == 1) ? Wk2 : Wv2;

    v4f acc[4][4] = {};
    gemm_mainloop(Xh, Xl, Bh, Bh + NW, m0, nb0, As, Bs, acc);

    const int tid  = threadIdx.x;
    const int wave = tid >> 6, lane = tid & 63;
    const int col  = lane & 15, quad = lane >> 4;
    const int wr   = wave >> 1, wc = wave & 1;
    const int b    = m0 >> 11;
    const int h    = (nb0 + wc * 64) >> 6;
    const size_t bh = (size_t)b * NH + h;

    if (mat == 2) {
        #pragma unroll
        for (int nt = 0; nt < 4; nt++) {
            const int d = nt * 16 + col;
            #pragma unroll
            for (int mt = 0; mt < 4; mt++) {
                const int m = m0 + wr * 64 + mt * 16 + quad * 4;
                const int s = m & (SEQN - 1);
                ushort4 pk = make_ushort4(f2h(acc[mt][nt][0]), f2h(acc[mt][nt][1]),
                                          f2h(acc[mt][nt][2]), f2h(acc[mt][nt][3]));
                *(ushort4*)&vth[(bh * DH + d) * SEQN + s] = pk;
            }
        }
        return;
    }

    float vsum[4] = {0.f, 0.f, 0.f, 0.f};
    #pragma unroll
    for (int mt = 0; mt < 4; mt++) {
        #pragma unroll
        for (int nt = 0; nt < 4; nt++) {
            const int d = nt * 16 + col;
            #pragma unroll
            for (int r = 0; r < 4; r++) {
                const int m = m0 + wr * 64 + mt * 16 + quad * 4 + r;
                const int s = m & (SEQN - 1);
                const float part = acc[mt][nt ^ 2][r];
                const float2 sc = tab[(s << 5) + (d & 31)];
                const float val = (d < 32) ? acc[mt][nt][r] * sc.y - part * sc.x
                                           : acc[mt][nt][r] * sc.y + part * sc.x;
                const size_t idx = (bh * SEQN + s) * DH + d;
                if (mat == 0) {
                    q32[idx] = val;
                } else {
                    kh16[idx] = f2h(val);
                    vsum[nt] += val;
                }
            }
        }
    }
    if (mat == 1) {
        #pragma unroll
        for (int nt = 0; nt < 4; nt++) {
            float v = vsum[nt];
            v += __shfl_xor(v, 16);
            v += __shfl_xor(v, 32);
            if (quad == 0) psum[wr][wc][nt * 16 + col] = v;
        }
        __syncthreads();
        if (tid < 128) {
            const int wc2 = tid >> 6, d = tid & 63;
            const float s2 = psum[0][wc2][d] + psum[1][wc2][d];
            const int h2 = (nb0 + wc2 * 64) >> 6;
            const int nblk = (m0 & (SEQN - 1)) >> 8;
            const int half = (m0 >> 7) & 1;
            partial[((((size_t)b * NH + h2) * NB + nblk) * 2 + half) * 64 + d] = s2;
        }
    }
}

// ---------------------------------------------------------------------------
__global__ __launch_bounds__(256)
void out_gemm_mfma_k(const u16* __restrict__ Ah, const u16* __restrict__ Wo2,
                     float* __restrict__ C)
{
    __shared__ u16 As[128 * 64];
    __shared__ u16 Bs[128 * 64];

    const int NW = HID * HID;
    const int id    = blockIdx.x;
    const int xcd   = id & 7, loc = id >> 3;
    const int mtile = xcd * 4 + (loc & 3);
    const int ntile = loc >> 2;
    const int m0 = mtile * 128;
    const int n0 = ntile * 128;

    v4f acc[4][4] = {};
    gemm_mainloop2(Ah, Wo2, Wo2 + NW, m0, n0, As, Bs, acc);

    const int tid  = threadIdx.x;
    const int wave = tid >> 6, lane = tid & 63;
    const int col  = lane & 15, quad = lane >> 4;
    const int wr   = wave >> 1, wc = wave & 1;

    #pragma unroll
    for (int mt = 0; mt < 4; mt++)
        #pragma unroll
        for (int nt = 0; nt < 4; nt++)
            #pragma unroll
            for (int r = 0; r < 4; r++) {
                const int m = m0 + wr * 64 + mt * 16 + quad * 4 + r;
                C[(size_t)m * HID + n0 + wc * 64 + nt * 16 + col] = acc[mt][nt][r];
            }
}

// ---------------------------------------------------------------------------
__global__ __launch_bounds__(64)
void reps_reduce_k(const float* __restrict__ partial, float* __restrict__ reps)
{
    const int bhn = blockIdx.x;
    const int d = threadIdx.x;
    const float* p = &partial[(size_t)bhn * 128 + d];
    double s = (double)p[0] + (double)p[64];
    reps[(size_t)bhn * 64 + d] = (float)(s * (1.0 / 256.0));
}

// ---------------------------------------------------------------------------
__global__ __launch_bounds__(128)
void select_topk_k(const float* __restrict__ qg, const float* __restrict__ reps,
                   unsigned* __restrict__ selm)
{
    __shared__ float rs[NB][DH];
    const int bh = blockIdx.y;
    const int tid = threadIdx.x;
    for (int idx = tid; idx < NB * DH; idx += 128)
        rs[idx >> 6][idx & 63] = reps[(size_t)bh * NB * DH + idx];
    __syncthreads();

    const int qq = blockIdx.x * 128 + tid;
    const float* qv = &qg[((size_t)bh * SEQN + qq) * DH];
    float qr[DH];
    #pragma unroll
    for (int c = 0; c < 16; c++) {
        float4 t = *(const float4*)&qv[c * 4];
        qr[c*4+0]=t.x; qr[c*4+1]=t.y; qr[c*4+2]=t.z; qr[c*4+3]=t.w;
    }
    const int cur = qq >> 8;
    double sc[NB];
    #pragma unroll
    for (int n = 0; n < NB; n++) {
        double ssum = 0.0;
        for (int d = 0; d < DH; d++) ssum += (double)qr[d] * (double)rs[n][d];
        sc[n] = ssum * 0.125;
    }
    for (int n = cur + 1; n < NB; n++) sc[n] = -1e300;
    sc[cur] = 1e300;
    unsigned mask = 0;
    for (int p = 0; p < 3; p++) {
        int bi = -1; double bv = 0.0;
        for (int n = 0; n < NB; n++) {
            if ((mask >> n) & 1) continue;
            if (bi < 0 || sc[n] > bv) { bi = n; bv = sc[n]; }
        }
        mask |= 1u << bi;
    }
    selm[(size_t)bh * SEQN + qq] = mask;
}

// ---------------------------------------------------------------------------
// f16 MFMA flash attention. K hi-only scores (Q kept 2-split). K and V both
// double-buffered via global_load_lds; single barrier per chunk; P wave-
// private LDS. LDS = 16K (K) + 16K (V) + 8K (P) = 40960 B -> 4 wgs/CU.
__global__ __launch_bounds__(256, 4)
void moba_attn_k(const float* __restrict__ q32, const u16* __restrict__ kh16,
                 const u16* __restrict__ vth, const unsigned* __restrict__ selm,
                 u16* __restrict__ aoh)
{
    __shared__ u16 kbuf[2][64 * 64];      // 16 KB dbuf (hi only)
    __shared__ u16 vbuf[2][64 * 64];      // 16 KB dbuf
    __shared__ u16 plds[4][16][64];       // 8 KB per-wave P
    unsigned* s_uni = (unsigned*)&vbuf[1][0];   // alias: dead until stage(1)

    const int id  = blockIdx.x;                 // 768
    const int xcd = id & 7, loc = id >> 3;      // 96 per XCD
    const int bh  = xcd * 3 + (loc >> 5);       // 3 bh per XCD (L2-local K/V)
    const int q0  = (loc & 31) * 64;
    const int cur = q0 >> 8;
    const int tid = threadIdx.x;
    const int wave = tid >> 6, lane = tid & 63;
    const int col = lane & 15, quad = lane >> 4;
    const int qw0 = q0 + wave * 16;
    const int qpos = qw0 + col;
    const size_t bhS = (size_t)bh * SEQN;
    const size_t bhV = (size_t)bh * DH;

    if (tid == 0) *s_uni = 0;
    __syncthreads();
    const unsigned mymask = selm[bhS + qw0 + col];
    unsigned uw = mymask;
    #pragma unroll
    for (int off = 1; off < 16; off <<= 1) uw |= __shfl_xor(uw, off);
    if (lane == 0) atomicOr(s_uni, uw);

    // Q fragments: f16 2-split, lo prescaled x2048
    v8hf qh[2], ql[2];
    #pragma unroll
    for (int ks = 0; ks < 2; ks++) {
        const float* qp = &q32[(bhS + qw0 + col) * DH + ks * 32 + quad * 8];
        float4 f0 = *(const float4*)qp;
        float4 f1 = *(const float4*)(qp + 4);
        float qf[8] = {f0.x, f0.y, f0.z, f0.w, f1.x, f1.y, f1.z, f1.w};
        union { u16 u[8]; v8hf h; } uh, ul;
        #pragma unroll
        for (int j = 0; j < 8; j++) {
            u16 hb = f2h(qf[j]);
            uh.u[j] = hb;
            ul.u[j] = f2h((qf[j] - h2f(hb)) * LO_SCALE);
        }
        qh[ks] = uh.h; ql[ks] = ul.h;
    }
    __syncthreads();
    const unsigned uni = __builtin_amdgcn_readfirstlane(*s_uni);

    // wg-uniform chunk enumeration
    int n_cur = __builtin_ctz(uni), c_cur = 0;
    int n_nxt = n_cur, c_nxt = 0;
    bool has_nxt = true;
    auto c2max = [&](int n) { return (n == cur) ? ((q0 + 63 - n * BLKSZ) >> 6) : 3; };
    auto advance = [&]() {
        if (c_nxt < c2max(n_nxt)) { c_nxt++; return; }
        has_nxt = false;
        for (int nn = n_nxt + 1; nn < NB; nn++)
            if ((uni >> nn) & 1) { n_nxt = nn; c_nxt = 0; has_nxt = true; return; }
    };
    advance();

    // staging (granule g = tid covers rows 0-31; +256 rows 32-63)
    const int sg_row0 = tid >> 3;
    const int sg_gl0  = (tid & 7) ^ (sg_row0 & 7);
    const int sg_row1 = (256 + tid) >> 3;
    const int sg_gl1  = ((256 + tid) & 7) ^ (sg_row1 & 7);
    auto stage = [&](int n, int c2, int buf) {
        const int kb = n * BLKSZ + c2 * 64;
        u16* kd = (u16*)kbuf[buf];
        u16* vd = (u16*)vbuf[buf];
        const size_t ks0 = (bhS + kb + sg_row0) * DH + sg_gl0 * 8;
        const size_t ks1 = (bhS + kb + sg_row1) * DH + sg_gl1 * 8;
        const size_t vs0 = (bhV + sg_row0) * SEQN + kb + sg_gl0 * 8;
        const size_t vs1 = (bhV + sg_row1) * SEQN + kb + sg_gl1 * 8;
        g2lds16(kh16 + ks0, kd + (wave * 64) * 8);
        g2lds16(kh16 + ks1, kd + (256 + wave * 64) * 8);
        g2lds16(vth + vs0, vd + (wave * 64) * 8);
        g2lds16(vth + vs1, vd + (256 + wave * 64) * 8);
    };

    const v4f zero4 = {0.f, 0.f, 0.f, 0.f};
    v4f oacc[4] = {zero4, zero4, zero4, zero4};
    float m_i = NEG_INF, l_i = 0.f;
    const int psw = (col & 7) << 1;

    stage(n_cur, c_cur, 0);
    int t = 0;
    while (true) {
        __syncthreads();                       // K/V(t) staged; buf (t+1)&1 free
        if (has_nxt) stage(n_nxt, c_nxt, (t + 1) & 1);

        const int n  = n_cur;
        const int kb = n * BLKSZ + c_cur * 64;
        const bool iscur = (n == cur);
        const float selinf = ((mymask >> n) & 1) ? 0.f : POS_INF;
        const bool need_mask = iscur && (kb + 63 > qw0);
        const u16* kd = (const u16*)kbuf[t & 1];
        const u16* vd = (const u16*)vbuf[t & 1];

        // ---- S^T[64k x 16q]: Kh*(Ql)/2048 + Kh*Qh
        v4f sf[4];
        #pragma unroll
        for (int mt = 0; mt < 4; mt++) {
            const int row = mt * 16 + col;
            const int r7 = row & 7;
            v8hf kh0 = ldhf8(&kd[(row * 8 + (quad ^ r7)) * 8]);
            v8hf kh1 = ldhf8(&kd[(row * 8 + ((4 + quad) ^ r7)) * 8]);
            v4f c = zero4;
            c = MFMA16(kh0, ql[0], c);
            c = MFMA16(kh1, ql[1], c);
            #pragma unroll
            for (int r = 0; r < 4; r++) c[r] *= LO_INV;
            c = MFMA16(kh0, qh[0], c);
            c = MFMA16(kh1, qh[1], c);
            sf[mt] = c;
        }

        if (need_mask) {
            #pragma unroll
            for (int mt = 0; mt < 4; mt++)
                #pragma unroll
                for (int r = 0; r < 4; r++) {
                    const int kidx = kb + mt * 16 + quad * 4 + r;
                    sf[mt][r] = (kidx <= qpos) ? sf[mt][r] : NEG_INF;
                }
        }

        // ---- softmax (exp2, folded 0.125 scale)
        float rm = NEG_INF;
        #pragma unroll
        for (int mt = 0; mt < 4; mt++)
            #pragma unroll
            for (int r = 0; r < 4; r++) rm = fmaxf(rm, sf[mt][r]);
        rm = fmaxf(rm, __shfl_xor(rm, 16));
        rm = fmaxf(rm, __shfl_xor(rm, 32));
        rm = rm - selinf;
        const float mnew  = fmaxf(m_i, rm);
        const float alpha = (m_i == NEG_INF) ? 0.f : exp2f((m_i - mnew) * EXP2C);
        const float biasC = ((mnew == NEG_INF) ? 0.f : mnew * EXP2C) + selinf;

        float lsum = 0.f;
        #pragma unroll
        for (int mt = 0; mt < 4; mt++) {
            ushort4 hv;
            #pragma unroll
            for (int r = 0; r < 4; r++) {
                float p = exp2f(fmaf(sf[mt][r], EXP2C, -biasC));
                lsum += p;
                u16 hu = f2h(p);
                if (r == 0) hv.x = hu;
                else if (r == 1) hv.y = hu;
                else if (r == 2) hv.z = hu;
                else hv.w = hu;
            }
            *(ushort4*)&plds[wave][col][((mt * 4 + quad) ^ psw) * 4] = hv;
        }
        lsum += __shfl_xor(lsum, 16);
        lsum += __shfl_xor(lsum, 32);
        l_i = l_i * alpha + lsum;
        m_i = mnew;

        float ar[4];
        #pragma unroll
        for (int r = 0; r < 4; r++) ar[r] = __shfl(alpha, quad * 4 + r, 16);
        #pragma unroll
        for (int nt = 0; nt < 4; nt++)
            #pragma unroll
            for (int r = 0; r < 4; r++) oacc[nt][r] *= ar[r];

        __threadfence_block();   // wave-private P write->read

        // ---- O += P * V  (V from LDS)
        #pragma unroll
        for (int ks2 = 0; ks2 < 2; ks2++) {
            v8hf ph = ldhf8(&plds[wave][col][((ks2 * 8 + quad * 2) ^ psw) * 4]);
            #pragma unroll
            for (int nt = 0; nt < 4; nt++) {
                const int row = nt * 16 + col;
                const int g = (ks2 * 4 + quad) ^ (row & 7);
                v8hf vh = ldhf8(&vd[(row * 8 + g) * 8]);
                oacc[nt] = MFMA16(ph, vh, oacc[nt]);
            }
        }

        if (!has_nxt) break;
        n_cur = n_nxt; c_cur = c_nxt;
        advance();
        t++;
    }

    // ---- epilogue: normalize, f16 store
    const int b = bh / NH, h = bh % NH;
    const float invl = 1.f / l_i;
    float ir[4];
    #pragma unroll
    for (int r = 0; r < 4; r++) ir[r] = __shfl(invl, quad * 4 + r, 16);
    #pragma unroll
    for (int nt = 0; nt < 4; nt++)
        #pragma unroll
        for (int r = 0; r < 4; r++) {
            const int qi = qw0 + quad * 4 + r;
            const size_t idx = ((size_t)b * SEQN + qi) * HID + h * DH + nt * 16 + col;
            aoh[idx] = f2h(oacc[nt][r] * ir[r]);
        }
}

// ---------------------------------------------------------------------------
extern "C" void kernel_launch(void* const* d_in, const int* in_sizes, int n_in,
                              void* d_out, int out_size, void* d_ws, size_t ws_size,
                              hipStream_t stream)
{
    const float* X  = (const float*)d_in[0];
    const float* Wq = (const float*)d_in[1];
    const float* Wk = (const float*)d_in[2];
    const float* Wv = (const float*)d_in[3];
    const float* Wo = (const float*)d_in[4];
    float* out = (float*)d_out;

    char* p = (char*)d_ws;
    float* q32 = (float*)p;                p += (size_t)NTOK*HID*4;
    u16* kh16 = (u16*)p;                   p += (size_t)NTOK*HID*2;
    u16* vth  = (u16*)p;                   p += (size_t)NTOK*HID*2;
    u16* Xh   = (u16*)p;                   p += (size_t)NTOK*HID*2;   // aoh alias
    u16* Xl   = (u16*)p;                   p += (size_t)NTOK*HID*2;
    u16* Wq2  = (u16*)p;                   p += (size_t)HID*HID*2*2;
    u16* Wk2  = (u16*)p;                   p += (size_t)HID*HID*2*2;
    u16* Wv2  = (u16*)p;                   p += (size_t)HID*HID*2*2;
    u16* Wo2  = (u16*)p;                   p += (size_t)HID*HID*2*2;
    float* partial = (float*)p;            p += (size_t)BATCH*NH*NB*2*64*4;
    float* reps    = (float*)p;            p += (size_t)BATCH*NH*NB*DH*4;
    unsigned* selm = (unsigned*)p;         p += (size_t)BATCH*NH*SEQN*4;
    float2* tab    = (float2*)p;           p += (size_t)SEQN*32*8;
    u16* aoh = Xh;   // X splits dead after projections

    const int NX = NTOK*HID;
    const int NW = HID*HID;

    rope_tab_k<<<dim3((SEQN*32+255)/256), 256, 0, stream>>>(tab);
    xsplit_k<<<dim3((NX+255)/256), 256, 0, stream>>>(X, NX, Xh, Xl);
    wsplit_k<<<dim3(NW/256, 4), 256, 0, stream>>>(Wq, Wk, Wv, Wo,
                                                  Wq2, Wk2, Wv2, Wo2);

    qkv_fused_gemm_k<<<dim3(576), 256, 0, stream>>>(
        Xh, Xl, Wq2, Wk2, Wv2, tab, q32, kh16, vth, partial);

    reps_reduce_k<<<dim3(BATCH*NH*NB), 64, 0, stream>>>(partial, reps);
    select_topk_k<<<dim3(SEQN/128, BATCH*NH), 128, 0, stream>>>(q32, reps, selm);

    moba_attn_k<<<dim3(BATCH*NH*(SEQN/64)), 256, 0, stream>>>(
        q32, kh16, vth, selm, aoh);

    out_gemm_mfma_k<<<dim3(192), 256, 0, stream>>>(aoh, Wo2, out);
}

// Round 10
// 247.814 us; speedup vs baseline: 1.2842x; 1.0876x over previous
//
#include <hip/hip_runtime.h>
#include <math.h>

// MoBA attention, round 9: qkv re-tiled 128x64 (1152 wgs = 4.5/CU), V drops
// to 2-product; out-proj 64x64 (768 wgs = 3/CU); preprocessing fused into
// one launch. Attention kernel unchanged from round 8 (passing).

#define HID   768
#define NH    12
#define DH    64
#define SEQN  2048
#define BATCH 2
#define NTOK  (BATCH*SEQN)   // 4096
#define NB    8
#define BLKSZ 256
#define NEG_INF (-__builtin_huge_valf())
#define POS_INF (__builtin_huge_valf())
#define LO_SCALE 2048.0f
#define LO_INV   (1.0f/2048.0f)
#define EXP2C    0.18033688f   // 0.125 * log2(e)

typedef unsigned short u16;
typedef _Float16 v8hf __attribute__((ext_vector_type(8)));
typedef float    v4f  __attribute__((ext_vector_type(4)));

__device__ __forceinline__ u16 f2h(float x) {
    _Float16 h = (_Float16)x;
    return __builtin_bit_cast(u16, h);
}
__device__ __forceinline__ float h2f(u16 u) {
    return (float)__builtin_bit_cast(_Float16, u);
}
__device__ __forceinline__ v8hf ldhf8(const u16* p) {
    return *reinterpret_cast<const v8hf*>(p);
}
__device__ __forceinline__ void g2lds16(const u16* g, u16* l) {
    __builtin_amdgcn_global_load_lds(
        (const __attribute__((address_space(1))) void*)g,
        (__attribute__((address_space(3))) void*)l, 16, 0, 0);
}
#define MFMA16(a, b, c) __builtin_amdgcn_mfma_f32_16x16x32_f16(a, b, c, 0, 0, 0)

// ---------------------------------------------------------------------------
// Fused preprocessing: X split (blocks 0-12287), W splits (12288-21503),
// RoPE table (21504-21759).
__global__ __launch_bounds__(256)
void preproc_k(const float* __restrict__ X,  const float* __restrict__ Wq,
               const float* __restrict__ Wk, const float* __restrict__ Wv,
               const float* __restrict__ Wo, float2* __restrict__ tab,
               u16* __restrict__ Xh, u16* __restrict__ Xl,
               u16* __restrict__ Wq2, u16* __restrict__ Wk2,
               u16* __restrict__ Wv2, u16* __restrict__ Wo2)
{
    const int NW = HID * HID;
    const int id = blockIdx.x;
    const int tid = threadIdx.x;
    if (id < 12288) {                       // X -> f16 hi/lo(x2048)
        const int i = id * 256 + tid;
        const float x = X[i];
        const u16 h = f2h(x);
        Xh[i] = h;
        Xl[i] = f2h((x - h2f(h)) * LO_SCALE);
    } else if (id < 21504) {                // 4 weight splits
        const int j = (id - 12288) * 256 + tid;
        const int z = j / NW, i = j - z * NW;
        const float* src = (z == 0) ? Wq : (z == 1) ? Wk : (z == 2) ? Wv : Wo;
        u16* dst = (z == 0) ? Wq2 : (z == 1) ? Wk2 : (z == 2) ? Wv2 : Wo2;
        const float x = src[i];
        const u16 h = f2h(x);
        dst[i] = h;
        dst[i + NW] = f2h((x - h2f(h)) * LO_SCALE);
    } else {                                // RoPE table (numpy fp32 op order)
        const int i = (id - 21504) * 256 + tid;
        const int s = i >> 5, f = i & 31;
        const double y  = exp((double)f * (log(10000.0) / 32.0));
        const float yf = (float)y;
        const float invf = 1.0f / yf;
        const float ang  = (float)s * invf;
        tab[i] = make_float2((float)sin((double)ang), (float)cos((double)ang));
    }
}

// ---------------------------------------------------------------------------
// 128x64 LDS-staged mainloop: acc = [c_start==0: (Al*Bh)] + (Ah*Bl) scaled
// by 1/2048, + Ah*Bh. 4 waves each own 32m x 64n (full head in-wave).
__device__ __forceinline__
void qkv_mainloop(const u16* __restrict__ Ah, const u16* __restrict__ Al,
                  const u16* __restrict__ Bh, const u16* __restrict__ Bl,
                  int m0, int nb0, int c_start,
                  u16* As, u16* Bs, v4f acc[2][4])
{
    const int tid = threadIdx.x;
    const int w = tid >> 6, lane = tid & 63;
    const int col = lane & 15, quad = lane >> 4;

    int a_row[4], a_gl[4];
    #pragma unroll
    for (int r = 0; r < 4; r++) {
        const int g = r * 256 + tid;
        a_row[r] = g >> 3;
        a_gl[r]  = (g & 7) ^ (a_row[r] & 7);
    }
    int b_row[2], b_gl[2];
    #pragma unroll
    for (int r = 0; r < 2; r++) {
        const int g = r * 256 + tid;
        b_row[r] = g >> 3;
        b_gl[r]  = (g & 7) ^ (b_row[r] & 7);
    }

    for (int c = c_start; c < 3; c++) {
        const u16* Ap = (c == 0) ? Al : Ah;
        const u16* Bp = (c == 1) ? Bl : Bh;
        for (int itc = 0; itc < HID / 64; itc++) {
            const int k0 = itc * 64;
            __syncthreads();
            #pragma unroll
            for (int r = 0; r < 4; r++)
                g2lds16(Ap + (size_t)(m0 + a_row[r]) * HID + k0 + a_gl[r] * 8,
                        &As[(r * 256 + w * 64) * 8]);
            #pragma unroll
            for (int r = 0; r < 2; r++)
                g2lds16(Bp + (size_t)(nb0 + b_row[r]) * HID + k0 + b_gl[r] * 8,
                        &Bs[(r * 256 + w * 64) * 8]);
            __syncthreads();
            #pragma unroll
            for (int ks = 0; ks < 2; ks++) {
                v8hf af[2], bf_[4];
                #pragma unroll
                for (int mt = 0; mt < 2; mt++) {
                    const int row = w * 32 + mt * 16 + col;
                    const int gph = (ks * 4 + quad) ^ (row & 7);
                    af[mt] = ldhf8(&As[row * 64 + gph * 8]);
                }
                #pragma unroll
                for (int nt = 0; nt < 4; nt++) {
                    const int row = nt * 16 + col;
                    const int gph = (ks * 4 + quad) ^ (row & 7);
                    bf_[nt] = ldhf8(&Bs[row * 64 + gph * 8]);
                }
                #pragma unroll
                for (int mt = 0; mt < 2; mt++)
                    #pragma unroll
                    for (int nt = 0; nt < 4; nt++)
                        acc[mt][nt] = MFMA16(af[mt], bf_[nt], acc[mt][nt]);
            }
        }
        if (c == 1) {
            #pragma unroll
            for (int mt = 0; mt < 2; mt++)
                #pragma unroll
                for (int nt = 0; nt < 4; nt++)
                    #pragma unroll
                    for (int r = 0; r < 4; r++)
                        acc[mt][nt][r] *= LO_INV;
        }
    }
    __syncthreads();
}

// ---------------------------------------------------------------------------
// Fused QKV. grid = 1152: 36 n-tiles (Q 0-11, K 12-23, V 24-35) x 32 m-tiles,
// XCD-partitioned by m. V uses 2 products.
__global__ __launch_bounds__(256)
void qkv_fused_gemm_k(const u16* __restrict__ Xh, const u16* __restrict__ Xl,
                      const u16* __restrict__ Wq2, const u16* __restrict__ Wk2,
                      const u16* __restrict__ Wv2, const float2* __restrict__ tab,
                      float* __restrict__ q32, u16* __restrict__ kh16,
                      u16* __restrict__ vth, float* __restrict__ partial)
{
    __shared__ u16 As[128 * 64];   // 16 KB
    __shared__ u16 Bs[64 * 64];    // 8 KB
    __shared__ float psum[4][64];

    const int NW = HID * HID;
    const int id    = blockIdx.x;
    const int xcd   = id & 7, loc = id >> 3;      // 144 per XCD
    const int mtile = xcd * 4 + (loc & 3);
    const int ntile = loc >> 2;                   // 0..35
    const int m0  = mtile * 128;
    const int mat = ntile / 12;
    const int nb0 = (ntile - mat * 12) * 64;
    const u16* Bh = (mat == 0) ? Wq2 : (mat == 1) ? Wk2 : Wv2;

    v4f acc[2][4] = {};
    qkv_mainloop(Xh, Xl, Bh, Bh + NW, m0, nb0, (mat == 2) ? 1 : 0, As, Bs, acc);

    const int tid = threadIdx.x;
    const int w = tid >> 6, lane = tid & 63;
    const int col = lane & 15, quad = lane >> 4;
    const int b = m0 >> 11;
    const int h = nb0 >> 6;
    const size_t bh = (size_t)b * NH + h;

    if (mat == 2) {                // V: transposed f16 store
        #pragma unroll
        for (int nt = 0; nt < 4; nt++) {
            const int d = nt * 16 + col;
            #pragma unroll
            for (int mt = 0; mt < 2; mt++) {
                const int m = m0 + w * 32 + mt * 16 + quad * 4;
                const int s = m & (SEQN - 1);
                ushort4 pk = make_ushort4(f2h(acc[mt][nt][0]), f2h(acc[mt][nt][1]),
                                          f2h(acc[mt][nt][2]), f2h(acc[mt][nt][3]));
                *(ushort4*)&vth[(bh * DH + d) * SEQN + s] = pk;
            }
        }
        return;
    }

    // Q/K: RoPE (partner dim d^32 = acc[mt][nt^2], same lane)
    float vsum[4] = {0.f, 0.f, 0.f, 0.f};
    #pragma unroll
    for (int mt = 0; mt < 2; mt++) {
        #pragma unroll
        for (int nt = 0; nt < 4; nt++) {
            const int d = nt * 16 + col;
            #pragma unroll
            for (int r = 0; r < 4; r++) {
                const int m = m0 + w * 32 + mt * 16 + quad * 4 + r;
                const int s = m & (SEQN - 1);
                const float part = acc[mt][nt ^ 2][r];
                const float2 sc = tab[(s << 5) + (d & 31)];
                const float val = (d < 32) ? acc[mt][nt][r] * sc.y - part * sc.x
                                           : acc[mt][nt][r] * sc.y + part * sc.x;
                const size_t idx = (bh * SEQN + s) * DH + d;
                if (mat == 0) {
                    q32[idx] = val;
                } else {
                    kh16[idx] = f2h(val);
                    vsum[nt] += val;
                }
            }
        }
    }
    if (mat == 1) {                // deterministic 128-token block partials
        #pragma unroll
        for (int nt = 0; nt < 4; nt++) {
            float v = vsum[nt];
            v += __shfl_xor(v, 16);
            v += __shfl_xor(v, 32);
            if (quad == 0) psum[w][nt * 16 + col] = v;
        }
        __syncthreads();
        if (tid < 64) {
            const float s4 = (psum[0][tid] + psum[1][tid])
                           + (psum[2][tid] + psum[3][tid]);
            const int nblk = (m0 & (SEQN - 1)) >> 8;
            const int half = (m0 >> 7) & 1;
            partial[((bh * NB + nblk) * 2 + half) * 64 + tid] = s4;
        }
    }
}

// ---------------------------------------------------------------------------
// Output projection: 64x64 tiles, 768 wgs (3/CU), 2-product.
__global__ __launch_bounds__(256)
void out_gemm_mfma_k(const u16* __restrict__ Ah, const u16* __restrict__ Wo2,
                     float* __restrict__ C)
{
    __shared__ u16 As[64 * 64];
    __shared__ u16 Bs[64 * 64];

    const int NW = HID * HID;
    const int id    = blockIdx.x;                 // 768
    const int xcd   = id & 7, loc = id >> 3;      // 96 per XCD
    const int mtile = xcd * 8 + (loc & 7);        // 64 m-tiles
    const int ntile = loc >> 3;                   // 0..11
    const int m0 = mtile * 64, n0 = ntile * 64;
    const int tid = threadIdx.x;
    const int w = tid >> 6, lane = tid & 63;
    const int col = lane & 15, quad = lane >> 4;

    const int r0 = tid >> 3,         gl0 = (tid & 7) ^ (r0 & 7);
    const int r1 = (256 + tid) >> 3, gl1 = ((256 + tid) & 7) ^ (r1 & 7);

    v4f acc[4] = {};
    #pragma unroll
    for (int c = 0; c < 2; c++) {
        const u16* Bp = (c == 0) ? (Wo2 + NW) : Wo2;   // lo first, then scale
        for (int itc = 0; itc < HID / 64; itc++) {
            const int k0 = itc * 64;
            __syncthreads();
            g2lds16(Ah + (size_t)(m0 + r0) * HID + k0 + gl0 * 8, &As[(w * 64) * 8]);
            g2lds16(Ah + (size_t)(m0 + r1) * HID + k0 + gl1 * 8, &As[(256 + w * 64) * 8]);
            g2lds16(Bp + (size_t)(n0 + r0) * HID + k0 + gl0 * 8, &Bs[(w * 64) * 8]);
            g2lds16(Bp + (size_t)(n0 + r1) * HID + k0 + gl1 * 8, &Bs[(256 + w * 64) * 8]);
            __syncthreads();
            #pragma unroll
            for (int ks = 0; ks < 2; ks++) {
                const int arow = w * 16 + col;
                v8hf a = ldhf8(&As[arow * 64 + (((ks * 4 + quad) ^ (arow & 7))) * 8]);
                #pragma unroll
                for (int nt = 0; nt < 4; nt++) {
                    const int row = nt * 16 + col;
                    v8hf bb = ldhf8(&Bs[row * 64 + (((ks * 4 + quad) ^ (row & 7))) * 8]);
                    acc[nt] = MFMA16(a, bb, acc[nt]);
                }
            }
        }
        if (c == 0) {
            #pragma unroll
            for (int nt = 0; nt < 4; nt++)
                #pragma unroll
                for (int r = 0; r < 4; r++)
                    acc[nt][r] *= LO_INV;
        }
    }

    #pragma unroll
    for (int nt = 0; nt < 4; nt++)
        #pragma unroll
        for (int r = 0; r < 4; r++) {
            const int m = m0 + w * 16 + quad * 4 + r;
            C[(size_t)m * HID + n0 + nt * 16 + col] = acc[nt][r];
        }
}

// ---------------------------------------------------------------------------
__global__ __launch_bounds__(64)
void reps_reduce_k(const float* __restrict__ partial, float* __restrict__ reps)
{
    const int bhn = blockIdx.x;
    const int d = threadIdx.x;
    const float* p = &partial[(size_t)bhn * 128 + d];
    double s = (double)p[0] + (double)p[64];
    reps[(size_t)bhn * 64 + d] = (float)(s * (1.0 / 256.0));
}

// ---------------------------------------------------------------------------
__global__ __launch_bounds__(128)
void select_topk_k(const float* __restrict__ qg, const float* __restrict__ reps,
                   unsigned* __restrict__ selm)
{
    __shared__ float rs[NB][DH];
    const int bh = blockIdx.y;
    const int tid = threadIdx.x;
    for (int idx = tid; idx < NB * DH; idx += 128)
        rs[idx >> 6][idx & 63] = reps[(size_t)bh * NB * DH + idx];
    __syncthreads();

    const int qq = blockIdx.x * 128 + tid;
    const float* qv = &qg[((size_t)bh * SEQN + qq) * DH];
    float qr[DH];
    #pragma unroll
    for (int c = 0; c < 16; c++) {
        float4 t = *(const float4*)&qv[c * 4];
        qr[c*4+0]=t.x; qr[c*4+1]=t.y; qr[c*4+2]=t.z; qr[c*4+3]=t.w;
    }
    const int cur = qq >> 8;
    double sc[NB];
    #pragma unroll
    for (int n = 0; n < NB; n++) {
        double ssum = 0.0;
        for (int d = 0; d < DH; d++) ssum += (double)qr[d] * (double)rs[n][d];
        sc[n] = ssum * 0.125;
    }
    for (int n = cur + 1; n < NB; n++) sc[n] = -1e300;
    sc[cur] = 1e300;
    unsigned mask = 0;
    for (int p = 0; p < 3; p++) {
        int bi = -1; double bv = 0.0;
        for (int n = 0; n < NB; n++) {
            if ((mask >> n) & 1) continue;
            if (bi < 0 || sc[n] > bv) { bi = n; bv = sc[n]; }
        }
        mask |= 1u << bi;
    }
    selm[(size_t)bh * SEQN + qq] = mask;
}

// ---------------------------------------------------------------------------
// f16 MFMA flash attention (round-8 structure, unchanged).
__global__ __launch_bounds__(256, 4)
void moba_attn_k(const float* __restrict__ q32, const u16* __restrict__ kh16,
                 const u16* __restrict__ vth, const unsigned* __restrict__ selm,
                 u16* __restrict__ aoh)
{
    __shared__ u16 kbuf[2][64 * 64];
    __shared__ u16 vbuf[2][64 * 64];
    __shared__ u16 plds[4][16][64];
    unsigned* s_uni = (unsigned*)&vbuf[1][0];

    const int id  = blockIdx.x;
    const int xcd = id & 7, loc = id >> 3;
    const int bh  = xcd * 3 + (loc >> 5);
    const int q0  = (loc & 31) * 64;
    const int cur = q0 >> 8;
    const int tid = threadIdx.x;
    const int wave = tid >> 6, lane = tid & 63;
    const int col = lane & 15, quad = lane >> 4;
    const int qw0 = q0 + wave * 16;
    const int qpos = qw0 + col;
    const size_t bhS = (size_t)bh * SEQN;
    const size_t bhV = (size_t)bh * DH;

    if (tid == 0) *s_uni = 0;
    __syncthreads();
    const unsigned mymask = selm[bhS + qw0 + col];
    unsigned uw = mymask;
    #pragma unroll
    for (int off = 1; off < 16; off <<= 1) uw |= __shfl_xor(uw, off);
    if (lane == 0) atomicOr(s_uni, uw);

    v8hf qh[2], ql[2];
    #pragma unroll
    for (int ks = 0; ks < 2; ks++) {
        const float* qp = &q32[(bhS + qw0 + col) * DH + ks * 32 + quad * 8];
        float4 f0 = *(const float4*)qp;
        float4 f1 = *(const float4*)(qp + 4);
        float qf[8] = {f0.x, f0.y, f0.z, f0.w, f1.x, f1.y, f1.z, f1.w};
        union { u16 u[8]; v8hf h; } uh, ul;
        #pragma unroll
        for (int j = 0; j < 8; j++) {
            u16 hb = f2h(qf[j]);
            uh.u[j] = hb;
            ul.u[j] = f2h((qf[j] - h2f(hb)) * LO_SCALE);
        }
        qh[ks] = uh.h; ql[ks] = ul.h;
    }
    __syncthreads();
    const unsigned uni = __builtin_amdgcn_readfirstlane(*s_uni);

    int n_cur = __builtin_ctz(uni), c_cur = 0;
    int n_nxt = n_cur, c_nxt = 0;
    bool has_nxt = true;
    auto c2max = [&](int n) { return (n == cur) ? ((q0 + 63 - n * BLKSZ) >> 6) : 3; };
    auto advance = [&]() {
        if (c_nxt < c2max(n_nxt)) { c_nxt++; return; }
        has_nxt = false;
        for (int nn = n_nxt + 1; nn < NB; nn++)
            if ((uni >> nn) & 1) { n_nxt = nn; c_nxt = 0; has_nxt = true; return; }
    };
    advance();

    const int sg_row0 = tid >> 3;
    const int sg_gl0  = (tid & 7) ^ (sg_row0 & 7);
    const int sg_row1 = (256 + tid) >> 3;
    const int sg_gl1  = ((256 + tid) & 7) ^ (sg_row1 & 7);
    auto stage = [&](int n, int c2, int buf) {
        const int kb = n * BLKSZ + c2 * 64;
        u16* kd = (u16*)kbuf[buf];
        u16* vd = (u16*)vbuf[buf];
        const size_t ks0 = (bhS + kb + sg_row0) * DH + sg_gl0 * 8;
        const size_t ks1 = (bhS + kb + sg_row1) * DH + sg_gl1 * 8;
        const size_t vs0 = (bhV + sg_row0) * SEQN + kb + sg_gl0 * 8;
        const size_t vs1 = (bhV + sg_row1) * SEQN + kb + sg_gl1 * 8;
        g2lds16(kh16 + ks0, kd + (wave * 64) * 8);
        g2lds16(kh16 + ks1, kd + (256 + wave * 64) * 8);
        g2lds16(vth + vs0, vd + (wave * 64) * 8);
        g2lds16(vth + vs1, vd + (256 + wave * 64) * 8);
    };

    const v4f zero4 = {0.f, 0.f, 0.f, 0.f};
    v4f oacc[4] = {zero4, zero4, zero4, zero4};
    float m_i = NEG_INF, l_i = 0.f;
    const int psw = (col & 7) << 1;

    stage(n_cur, c_cur, 0);
    int t = 0;
    while (true) {
        __syncthreads();
        if (has_nxt) stage(n_nxt, c_nxt, (t + 1) & 1);

        const int n  = n_cur;
        const int kb = n * BLKSZ + c_cur * 64;
        const bool iscur = (n == cur);
        const float selinf = ((mymask >> n) & 1) ? 0.f : POS_INF;
        const bool need_mask = iscur && (kb + 63 > qw0);
        const u16* kd = (const u16*)kbuf[t & 1];
        const u16* vd = (const u16*)vbuf[t & 1];

        v4f sf[4];
        #pragma unroll
        for (int mt = 0; mt < 4; mt++) {
            const int row = mt * 16 + col;
            const int r7 = row & 7;
            v8hf kh0 = ldhf8(&kd[(row * 8 + (quad ^ r7)) * 8]);
            v8hf kh1 = ldhf8(&kd[(row * 8 + ((4 + quad) ^ r7)) * 8]);
            v4f c = zero4;
            c = MFMA16(kh0, ql[0], c);
            c = MFMA16(kh1, ql[1], c);
            #pragma unroll
            for (int r = 0; r < 4; r++) c[r] *= LO_INV;
            c = MFMA16(kh0, qh[0], c);
            c = MFMA16(kh1, qh[1], c);
            sf[mt] = c;
        }

        if (need_mask) {
            #pragma unroll
            for (int mt = 0; mt < 4; mt++)
                #pragma unroll
                for (int r = 0; r < 4; r++) {
                    const int kidx = kb + mt * 16 + quad * 4 + r;
                    sf[mt][r] = (kidx <= qpos) ? sf[mt][r] : NEG_INF;
                }
        }

        float rm = NEG_INF;
        #pragma unroll
        for (int mt = 0; mt < 4; mt++)
            #pragma unroll
            for (int r = 0; r < 4; r++) rm = fmaxf(rm, sf[mt][r]);
        rm = fmaxf(rm, __shfl_xor(rm, 16));
        rm = fmaxf(rm, __shfl_xor(rm, 32));
        rm = rm - selinf;
        const float mnew  = fmaxf(m_i, rm);
        const float alpha = (m_i == NEG_INF) ? 0.f : exp2f((m_i - mnew) * EXP2C);
        const float biasC = ((mnew == NEG_INF) ? 0.f : mnew * EXP2C) + selinf;

        float lsum = 0.f;
        #pragma unroll
        for (int mt = 0; mt < 4; mt++) {
            ushort4 hv;
            #pragma unroll
            for (int r = 0; r < 4; r++) {
                float p = exp2f(fmaf(sf[mt][r], EXP2C, -biasC));
                lsum += p;
                u16 hu = f2h(p);
                if (r == 0) hv.x = hu;
                else if (r == 1) hv.y = hu;
                else if (r == 2) hv.z = hu;
                else hv.w = hu;
            }
            *(ushort4*)&plds[wave][col][((mt * 4 + quad) ^ psw) * 4] = hv;
        }
        lsum += __shfl_xor(lsum, 16);
        lsum += __shfl_xor(lsum, 32);
        l_i = l_i * alpha + lsum;
        m_i = mnew;

        float ar[4];
        #pragma unroll
        for (int r = 0; r < 4; r++) ar[r] = __shfl(alpha, quad * 4 + r, 16);
        #pragma unroll
        for (int nt = 0; nt < 4; nt++)
            #pragma unroll
            for (int r = 0; r < 4; r++) oacc[nt][r] *= ar[r];

        __threadfence_block();

        #pragma unroll
        for (int ks2 = 0; ks2 < 2; ks2++) {
            v8hf ph = ldhf8(&plds[wave][col][((ks2 * 8 + quad * 2) ^ psw) * 4]);
            #pragma unroll
            for (int nt = 0; nt < 4; nt++) {
                const int row = nt * 16 + col;
                const int g = (ks2 * 4 + quad) ^ (row & 7);
                v8hf vh = ldhf8(&vd[(row * 8 + g) * 8]);
                oacc[nt] = MFMA16(ph, vh, oacc[nt]);
            }
        }

        if (!has_nxt) break;
        n_cur = n_nxt; c_cur = c_nxt;
        advance();
        t++;
    }

    const int b = bh / NH, h = bh % NH;
    const float invl = 1.f / l_i;
    float ir[4];
    #pragma unroll
    for (int r = 0; r < 4; r++) ir[r] = __shfl(invl, quad * 4 + r, 16);
    #pragma unroll
    for (int nt = 0; nt < 4; nt++)
        #pragma unroll
        for (int r = 0; r < 4; r++) {
            const int qi = qw0 + quad * 4 + r;
            const size_t idx = ((size_t)b * SEQN + qi) * HID + h * DH + nt * 16 + col;
            aoh[idx] = f2h(oacc[nt][r] * ir[r]);
        }
}

// ---------------------------------------------------------------------------
extern "C" void kernel_launch(void* const* d_in, const int* in_sizes, int n_in,
                              void* d_out, int out_size, void* d_ws, size_t ws_size,
                              hipStream_t stream)
{
    const float* X  = (const float*)d_in[0];
    const float* Wq = (const float*)d_in[1];
    const float* Wk = (const float*)d_in[2];
    const float* Wv = (const float*)d_in[3];
    const float* Wo = (const float*)d_in[4];
    float* out = (float*)d_out;

    char* p = (char*)d_ws;
    float* q32 = (float*)p;                p += (size_t)NTOK*HID*4;
    u16* kh16 = (u16*)p;                   p += (size_t)NTOK*HID*2;
    u16* vth  = (u16*)p;                   p += (size_t)NTOK*HID*2;
    u16* Xh   = (u16*)p;                   p += (size_t)NTOK*HID*2;   // aoh alias
    u16* Xl   = (u16*)p;                   p += (size_t)NTOK*HID*2;
    u16* Wq2  = (u16*)p;                   p += (size_t)HID*HID*2*2;
    u16* Wk2  = (u16*)p;                   p += (size_t)HID*HID*2*2;
    u16* Wv2  = (u16*)p;                   p += (size_t)HID*HID*2*2;
    u16* Wo2  = (u16*)p;                   p += (size_t)HID*HID*2*2;
    float* partial = (float*)p;            p += (size_t)BATCH*NH*NB*2*64*4;
    float* reps    = (float*)p;            p += (size_t)BATCH*NH*NB*DH*4;
    unsigned* selm = (unsigned*)p;         p += (size_t)BATCH*NH*SEQN*4;
    float2* tab    = (float2*)p;           p += (size_t)SEQN*32*8;
    u16* aoh = Xh;   // X splits dead after projections

    preproc_k<<<dim3(21760), 256, 0, stream>>>(X, Wq, Wk, Wv, Wo, tab,
                                               Xh, Xl, Wq2, Wk2, Wv2, Wo2);

    qkv_fused_gemm_k<<<dim3(1152), 256, 0, stream>>>(
        Xh, Xl, Wq2, Wk2, Wv2, tab, q32, kh16, vth, partial);

    reps_reduce_k<<<dim3(BATCH*NH*NB), 64, 0, stream>>>(partial, reps);
    select_topk_k<<<dim3(SEQN/128, BATCH*NH), 128, 0, stream>>>(q32, reps, selm);

    moba_attn_k<<<dim3(BATCH*NH*(SEQN/64)), 256, 0, stream>>>(
        q32, kh16, vth, selm, aoh);

    out_gemm_mfma_k<<<dim3(768), 256, 0, stream>>>(aoh, Wo2, out);
}